// Round 12
// baseline (166.068 us; speedup 1.0000x reference)
//
#include <hip/hip_runtime.h>
#include <math.h>

namespace {

constexpr int kB    = 16384;
constexpr int kS0   = 7;
constexpr int kS1   = 7;
constexpr int kD    = 30;
constexpr int kCells = kB * kS0 * kS1;   // 802816
constexpr int TPB   = 256;
constexpr int T     = 4;                 // tiles per block, register-pipelined
constexpr int NBLK  = kCells / (TPB * T);// 784 (exact)
constexpr float kInv7 = 1.0f / 7.0f;
constexpr float kWC = 5.0f;
constexpr float kWN = 0.5f;

__device__ __forceinline__ float frcp(float x) {
    return __builtin_amdgcn_rcpf(x);     // v_rcp_f32, ~1e-7 rel err (2% tol)
}

__device__ __forceinline__ float sigm(float x) {
    return frcp(1.0f + __expf(-x));
}

// In-register double-buffered pipeline, NO LDS, NO barriers.
// r4/r8: register prefetch across __syncthreads always spills -> there is no
// __syncthreads here, removing the spill trigger. launch_bounds(256,3):
// VGPR cap ~170 (pipeline needs ~110-120; r8's 128 cap may have forced its
// spill). sched_barrier(0) pins each tile's 18-load batch ahead of the
// previous tile's compute -> loads in flight UNDER compute.
__global__ void __launch_bounds__(TPB, 3) yolo_loss_kernel(
    const float* __restrict__ pred,
    const int*   __restrict__ grid,
    const float* __restrict__ tbox,
    const int*   __restrict__ tcls,
    float* __restrict__ partials)   // NBLK f32 in d_ws (all overwritten)
{
    __shared__ float wsum[TPB / 64];      // reduction only (16 B)

    const int tid  = threadIdx.x;
    const int wave = tid >> 6;
    const int lane = tid & 63;

    float2 r[2][kD / 2];                  // parity-indexed double buffer
    float4 tb[2];
    int    gg[2], tc[2];

    auto load_tile = [&](int t, int buf) {
        const int cell = (blockIdx.x * T + t) * TPB + tid;
        const float2* __restrict__ p2 =
            reinterpret_cast<const float2*>(pred + (size_t)cell * kD);
        #pragma unroll
        for (int q = 0; q < kD / 2; ++q) r[buf][q] = p2[q];
        tb[buf] = reinterpret_cast<const float4*>(tbox)[cell];
        gg[buf] = grid[cell];
        tc[buf] = tcls[cell];
    };

    auto compute_tile = [&](int t, int buf) -> float {
        const int cell = (blockIdx.x * T + t) * TPB + tid;

        float f[kD];
        #pragma unroll
        for (int q = 0; q < kD / 2; ++q) {
            f[2 * q]     = r[buf][q].x;
            f[2 * q + 1] = r[buf][q].y;
        }

        const int cj = cell % kS1;        // column -> xg
        const int ci = (cell / kS1) % kS0;// row    -> yg
        const float tox = tb[buf].x, toy = tb[buf].y;
        const float tw  = tb[buf].z, th  = tb[buf].w;
        const int g2 = gg[buf], tcv = tc[buf];

        const float conf0 = sigm(f[0]);
        const float conf1 = sigm(f[1]);
        float pbx[2], pby[2], pbw[2], pbh[2];
        #pragma unroll
        for (int k = 0; k < 2; ++k) {
            pbx[k] = sigm(f[2 + 4 * k + 0]);
            pby[k] = sigm(f[2 + 4 * k + 1]);
            pbw[k] = sigm(f[2 + 4 * k + 2]);
            pbh[k] = sigm(f[2 + 4 * k + 3]);
        }

        // softmax over 20 classes, no max-subtraction (inputs ~N(0,1):
        // exp <= ~e^6, 20-term fp32 sum nowhere near overflow)
        float csum = 0.0f, et = 0.0f;
        #pragma unroll
        for (int q = 0; q < 20; ++q) {
            const float e = __expf(f[10 + q]);
            csum += e;
            et = (q == tcv) ? e : et;     // constant q -> cndmask
        }
        const float cls_t = et * frcp(csum);

        const float x = (float)cj, y = (float)ci;
        const float tcx = (x + tox) * kInv7;
        const float tcy = (y + toy) * kInv7;
        const float thw = tw * 0.5f, thh = th * 0.5f;
        const float tarea = tw * th;

        float iou[2];
        #pragma unroll
        for (int k = 0; k < 2; ++k) {
            const float pcx = (x + pbx[k]) * kInv7;
            const float pcy = (y + pby[k]) * kInv7;
            const float pw = pbw[k], ph = pbh[k];
            const float tb_ = fminf(tcx + thw, pcx + pw * 0.5f) - fmaxf(tcx - thw, pcx - pw * 0.5f);
            const float lr_ = fminf(tcy + thh, pcy + ph * 0.5f) - fmaxf(tcy - thh, pcy - ph * 0.5f);
            float inter = tb_ * lr_;
            inter = (tb_ < 0.0f || lr_ < 0.0f) ? 0.0f : inter;
            iou[k] = inter * frcp(tarea + pw * ph - inter);
        }

        const bool b1 = (iou[1] > iou[0]); // tie -> box 0 (first-max)
        const float bx = b1 ? pbx[1] : pbx[0];
        const float by = b1 ? pby[1] : pby[0];
        const float bw = b1 ? pbw[1] : pbw[0];
        const float bh = b1 ? pbh[1] : pbh[0];
        const float conf_b = b1 ? conf1 : conf0;
        const float iou_b  = b1 ? iou[1] : iou[0];

        const float dx = bx - tox;
        const float dy = by - toy;
        const float dw = sqrtf(bw) - sqrtf(tw);
        const float dh = sqrtf(bh) - sqrtf(th);
        const float coord = dx * dx + dy * dy + dw * dw + dh * dh;
        const float d1 = conf_b - iou_b;
        const float d2 = 1.0f - cls_t;
        const float obj   = kWC * coord + d1 * d1 + d2 * d2;
        const float noobj = kWN * (conf0 * conf0 + conf1 * conf1);

        return (g2 == 1) ? obj : noobj;
    };

    // --- pipeline: load(t+1) issued before compute(t); full unroll makes
    // buffer indices compile-time (pure SSA, no physical copies).
    float v = 0.0f;
    load_tile(0, 0);
    #pragma unroll
    for (int t = 0; t < T; ++t) {
        const int cur = t & 1;
        if (t + 1 < T) load_tile(t + 1, cur ^ 1);
        __builtin_amdgcn_sched_barrier(0);    // loads stay ahead of compute
        v += compute_tile(t, cur);
    }

    // --- wave64 shuffle reduce, cross-wave via tiny LDS, plain store ---
    #pragma unroll
    for (int off = 32; off > 0; off >>= 1) v += __shfl_down(v, off, 64);
    if (lane == 0) wsum[wave] = v;
    __syncthreads();
    if (tid == 0) {
        partials[blockIdx.x] = wsum[0] + wsum[1] + wsum[2] + wsum[3];
    }
}

__global__ void __launch_bounds__(256) finish_kernel(
    const float* __restrict__ partials, float* __restrict__ out)
{
    __shared__ float wsum[4];
    const int tid = threadIdx.x;
    float v = 0.0f;
    for (int i = tid; i < NBLK; i += 256) v += partials[i];  // 4 iters
    #pragma unroll
    for (int off = 32; off > 0; off >>= 1) v += __shfl_down(v, off, 64);
    if ((tid & 63) == 0) wsum[tid >> 6] = v;
    __syncthreads();
    if (tid == 0) out[0] = (wsum[0] + wsum[1] + wsum[2] + wsum[3]) * (1.0f / kB);
}

} // namespace

extern "C" void kernel_launch(void* const* d_in, const int* in_sizes, int n_in,
                              void* d_out, int out_size, void* d_ws, size_t ws_size,
                              hipStream_t stream) {
    const float* pred = (const float*)d_in[0];
    const int*   grid = (const int*)d_in[1];
    const float* tbox = (const float*)d_in[2];
    const int*   tcls = (const int*)d_in[3];
    float* out      = (float*)d_out;
    float* partials = (float*)d_ws;       // NBLK f32; fully overwritten

    yolo_loss_kernel<<<NBLK, TPB, 0, stream>>>(pred, grid, tbox, tcls, partials);
    finish_kernel<<<1, 256, 0, stream>>>(partials, out);
}